// Round 1
// baseline (116.123 us; speedup 1.0000x reference)
//
#include <hip/hip_runtime.h>

// FastSamPredict bbox-from-masks: N=128 masks of H=1024 x W=1024 fp32 {0,1}.
// Output [N,4] float32 = [x1(min col), y1(min row), x2(max col), y2(max row)].
// Memory-bound streaming reduction over 512 MB.

constexpr int N_MASKS = 128;
constexpr int H = 1024;
constexpr int W = 1024;
constexpr int BLOCKS_PER_MASK = 16;
constexpr int THREADS = 256;
constexpr int UINT4_PER_MASK  = H * W / 4;                      // 262144
constexpr int UINT4_PER_BLOCK = UINT4_PER_MASK / BLOCKS_PER_MASK; // 16384
constexpr int ITERS = UINT4_PER_BLOCK / THREADS;                // 64

// Kernel 1: initialize d_out (as int32) with sentinels {W, H, -1, -1} per mask.
// Runs every call -> overwrites harness poison, deterministic.
__global__ void bbox_init(int* __restrict__ out_i) {
    int i = threadIdx.x;
    if (i < N_MASKS * 4) {
        int j = i & 3;
        out_i[i] = (j == 0) ? W : (j == 1) ? H : -1;
    }
}

// Kernel 2: per-block partial bbox over a 1/16 slice of one mask, then
// wave-level shfl_xor reduce + one atomic quad per wave.
__global__ __launch_bounds__(THREADS) void bbox_main(const uint4* __restrict__ masks,
                                                     int* __restrict__ out_i) {
    const int mask  = blockIdx.y;
    const int chunk = blockIdx.x;
    const uint4* base = masks + (size_t)mask * UINT4_PER_MASK
                              + (size_t)chunk * UINT4_PER_BLOCK;

    int minx = W, miny = H, maxx = -1, maxy = -1;

    #pragma unroll 4
    for (int it = 0; it < ITERS; ++it) {
        const int off = it * THREADS + (int)threadIdx.x;      // uint4 idx in block slice
        uint4 v = base[off];
        unsigned any = v.x | v.y | v.z | v.w;                 // values are 0 or 0x3f800000
        if (any) {
            const int e  = (chunk * UINT4_PER_BLOCK + off) << 2; // element idx in mask
            const int y  = e >> 10;        // / W
            const int x0 = e & (W - 1);    // % W
            // first/last set element within the 4-wide vector (branchless selects)
            int first = v.x ? 0 : (v.y ? 1 : (v.z ? 2 : 3));
            int last  = v.w ? 3 : (v.z ? 2 : (v.y ? 1 : 0));
            minx = min(minx, x0 + first);
            maxx = max(maxx, x0 + last);
            miny = min(miny, y);
            maxy = max(maxy, y);
        }
    }

    // 64-lane butterfly reduce (wave = 64 on CDNA)
    #pragma unroll
    for (int s = 32; s > 0; s >>= 1) {
        minx = min(minx, __shfl_xor(minx, s));
        miny = min(miny, __shfl_xor(miny, s));
        maxx = max(maxx, __shfl_xor(maxx, s));
        maxy = max(maxy, __shfl_xor(maxy, s));
    }

    if ((threadIdx.x & 63) == 0) {
        atomicMin(&out_i[mask * 4 + 0], minx);
        atomicMin(&out_i[mask * 4 + 1], miny);
        atomicMax(&out_i[mask * 4 + 2], maxx);
        atomicMax(&out_i[mask * 4 + 3], maxy);
    }
}

// Kernel 3: in-place int32 -> float32 convert of the 512 outputs.
__global__ void bbox_finalize(float* __restrict__ out_f) {
    int i = threadIdx.x;
    if (i < N_MASKS * 4) {
        int v = ((const int*)out_f)[i];
        out_f[i] = (float)v;
    }
}

extern "C" void kernel_launch(void* const* d_in, const int* in_sizes, int n_in,
                              void* d_out, int out_size, void* d_ws, size_t ws_size,
                              hipStream_t stream) {
    const uint4* masks = (const uint4*)d_in[0];
    int*   out_i = (int*)d_out;
    float* out_f = (float*)d_out;

    bbox_init<<<1, 512, 0, stream>>>(out_i);

    dim3 grid(BLOCKS_PER_MASK, N_MASKS);
    bbox_main<<<grid, THREADS, 0, stream>>>(masks, out_i);

    bbox_finalize<<<1, 512, 0, stream>>>(out_f);
}

// Round 2
// 16.725 us; speedup vs baseline: 6.9431x; 6.9431x over previous
//
#include <hip/hip_runtime.h>

// FastSamPredict bbox-from-masks, adaptive scan version.
// N=128 masks, H=W=1024 fp32 {0.0, 1.0}. Output [N,4] f32 = [x1,y1,x2,y2].
//
// Each block: one mask x 256-row slice. 256 threads = 4 fixed columns each
// (full 1024-wide row per iteration, wave reads 1 KB contiguous).
// Forward scan OR-accumulates columns; exits when all 4 owned columns seen
// (further rows cannot change x-bounds, miny already fixed). Backward scan
// from slice end finds maxy. Worst case scans all rows -> correct for any
// input; for random p=0.5 masks reads ~6% of the data.
//
// Outputs stored as float BIT PATTERNS via signed-int atomicMin/Max:
// all live coords are >= 0 so IEEE order == signed-int order; inits
// 1024.0f (min fields) / -1.0f (max fields) decode to the exact reference
// values for an empty mask. No finalize kernel needed.

constexpr int N_MASKS = 128;
constexpr int H = 1024;
constexpr int W = 1024;
constexpr int BLOCKS_PER_MASK = 4;
constexpr int ROWS_PER_BLOCK  = H / BLOCKS_PER_MASK;  // 256
constexpr int THREADS         = W / 4;                // 256 threads, 4 cols each
constexpr int ROW_STRIDE_U4   = W / 4;                // uint4 per row
constexpr int BATCH           = 4;
constexpr unsigned ONE_BITS   = 0x3f800000u;          // 1.0f

// Init d_out (as int32) with float bit patterns {1024.0f,1024.0f,-1.0f,-1.0f}.
__global__ void bbox_init(int* __restrict__ out_i) {
    int i = threadIdx.x;
    if (i < N_MASKS * 4) {
        out_i[i] = ((i & 3) < 2) ? 0x44800000 : 0xBF800000;  // 1024.0f : -1.0f
    }
}

__global__ __launch_bounds__(THREADS) void bbox_main(const uint4* __restrict__ masks,
                                                     int* __restrict__ out_i) {
    const int mask = blockIdx.y;
    const int r0   = blockIdx.x * ROWS_PER_BLOCK;
    const int r1   = r0 + ROWS_PER_BLOCK;
    const int t    = (int)threadIdx.x;
    const uint4* base = masks + (size_t)mask * (H * (size_t)W / 4) + t;

    unsigned ox = 0, oy = 0, oz = 0, ow = 0;  // column-OR for owned cols 4t..4t+3
    int miny = H, maxy = -1;
    int scanned = r1;  // first row NOT covered by the forward scan

    // ---- forward scan, batches of 4 independent row loads ----
    for (int r = r0; r < r1; r += BATCH) {
        uint4 v0 = base[(size_t)(r + 0) * ROW_STRIDE_U4];
        uint4 v1 = base[(size_t)(r + 1) * ROW_STRIDE_U4];
        uint4 v2 = base[(size_t)(r + 2) * ROW_STRIDE_U4];
        uint4 v3 = base[(size_t)(r + 3) * ROW_STRIDE_U4];
        unsigned a0 = v0.x | v0.y | v0.z | v0.w;
        unsigned a1 = v1.x | v1.y | v1.z | v1.w;
        unsigned a2 = v2.x | v2.y | v2.z | v2.w;
        unsigned a3 = v3.x | v3.y | v3.z | v3.w;
        miny = min(miny, a0 ? r + 0 : H);
        miny = min(miny, a1 ? r + 1 : H);
        miny = min(miny, a2 ? r + 2 : H);
        miny = min(miny, a3 ? r + 3 : H);
        maxy = max(maxy, a3 ? r + 3 : -1);
        maxy = max(maxy, a2 ? r + 2 : -1);
        maxy = max(maxy, a1 ? r + 1 : -1);
        maxy = max(maxy, a0 ? r + 0 : -1);
        ox |= v0.x | v1.x | v2.x | v3.x;
        oy |= v0.y | v1.y | v2.y | v3.y;
        oz |= v0.z | v1.z | v2.z | v3.z;
        ow |= v0.w | v1.w | v2.w | v3.w;
        if ((ox & oy & oz & ow) == ONE_BITS) {  // all owned columns seen
            scanned = r + BATCH;
            break;
        }
    }

    // ---- backward scan over unscanned rows [scanned, r1): find last any-row ----
    for (int rb = r1 - BATCH; rb >= scanned; rb -= BATCH) {
        uint4 v0 = base[(size_t)(rb + 0) * ROW_STRIDE_U4];
        uint4 v1 = base[(size_t)(rb + 1) * ROW_STRIDE_U4];
        uint4 v2 = base[(size_t)(rb + 2) * ROW_STRIDE_U4];
        uint4 v3 = base[(size_t)(rb + 3) * ROW_STRIDE_U4];
        unsigned a0 = v0.x | v0.y | v0.z | v0.w;
        unsigned a1 = v1.x | v1.y | v1.z | v1.w;
        unsigned a2 = v2.x | v2.y | v2.z | v2.w;
        unsigned a3 = v3.x | v3.y | v3.z | v3.w;
        int cand = -1;
        cand = max(cand, a0 ? rb + 0 : -1);
        cand = max(cand, a1 ? rb + 1 : -1);
        cand = max(cand, a2 ? rb + 2 : -1);
        cand = max(cand, a3 ? rb + 3 : -1);
        if (cand >= 0) { maxy = max(maxy, cand); break; }
    }

    // ---- x-bounds from the column OR ----
    int minx = W, maxx = -1;
    if (ox | oy | oz | ow) {
        int first = ox ? 0 : (oy ? 1 : (oz ? 2 : 3));
        int last  = ow ? 3 : (oz ? 2 : (oy ? 1 : 0));
        minx = 4 * t + first;
        maxx = 4 * t + last;
    }

    // ---- 64-lane butterfly reduce ----
    #pragma unroll
    for (int s = 32; s > 0; s >>= 1) {
        minx = min(minx, __shfl_xor(minx, s));
        miny = min(miny, __shfl_xor(miny, s));
        maxx = max(maxx, __shfl_xor(maxx, s));
        maxy = max(maxy, __shfl_xor(maxy, s));
    }

    // ---- per-wave atomics on float bit patterns (all live values >= 0) ----
    if ((threadIdx.x & 63) == 0) {
        atomicMin(&out_i[mask * 4 + 0], __float_as_int((float)minx)); // 1024 -> init, no-op
        atomicMin(&out_i[mask * 4 + 1], __float_as_int((float)miny));
        atomicMax(&out_i[mask * 4 + 2], __float_as_int((float)maxx)); // -1 -> init, no-op
        atomicMax(&out_i[mask * 4 + 3], __float_as_int((float)maxy));
    }
}

extern "C" void kernel_launch(void* const* d_in, const int* in_sizes, int n_in,
                              void* d_out, int out_size, void* d_ws, size_t ws_size,
                              hipStream_t stream) {
    const uint4* masks = (const uint4*)d_in[0];
    int* out_i = (int*)d_out;

    bbox_init<<<1, 512, 0, stream>>>(out_i);

    dim3 grid(BLOCKS_PER_MASK, N_MASKS);
    bbox_main<<<grid, THREADS, 0, stream>>>(masks, out_i);
}

// Round 3
// 9.658 us; speedup vs baseline: 12.0240x; 1.7318x over previous
//
#include <hip/hip_runtime.h>

// FastSamPredict bbox-from-masks, ends-only adaptive scan.
// N=128 masks of H=W=1024 fp32 {0.0,1.0}. Output [N,4] f32 = [x1,y1,x2,y2].
//
// Grid: (2 roles x 128 masks) blocks of ONE 64-lane wave.
//   role 0 (top):    scans rows downward, owns x1 = min set col, y1 = min set row
//   role 1 (bottom): scans rows upward,   owns x2 = max set col, y2 = max set row
//
// Exactness argument for the early break:
//   y1 is final once any non-empty row is seen scanning from the top (rows are
//   scanned in order, full width). x1=0 is final once column 0 is seen anywhere
//   (no column lies left of it). Symmetrically for y2 / x2=1023 from the bottom.
//   If the break never fires the loop scans ALL rows, leaving a complete
//   column-OR and full row coverage -> candX/lane_y computed below are exact
//   for any input, including empty masks ({1024,1024,-1,-1} like the ref).
//
// No atomics, no LDS, no second kernel: each block writes its 2 floats, all
// 512 outputs are written exactly once per launch (poison overwritten).

constexpr int N_MASKS = 128;
constexpr int H = 1024;
constexpr int W = 1024;
constexpr int U4_ROW = W / 4;   // 256 uint4 per row
constexpr int BATCH  = 8;       // rows per batch: P(col-0 unseen in 8 rows)=2^-8

__global__ __launch_bounds__(64)
void bbox_ends(const uint4* __restrict__ masks, float* __restrict__ out) {
    const int role = (int)blockIdx.x;        // 0 = top, 1 = bottom
    const int mask = (int)blockIdx.y;
    const int t    = (int)threadIdx.x;       // lane 0..63
    const uint4* __restrict__ base = masks + (size_t)mask * (H * (size_t)U4_ROW);

    // Column-OR accumulators: lane t covers cols {4t..4t+3} in 4 segments
    // (seg k = cols 256k+4t .. 256k+4t+3). Values are 0 or 0x3f800000.
    uint4 c0 = make_uint4(0,0,0,0), c1 = make_uint4(0,0,0,0),
          c2 = make_uint4(0,0,0,0), c3 = make_uint4(0,0,0,0);
    int lane_y = (role == 0) ? H : -1;       // first/last row with set pixel in lane's cols

    for (int b = 0; b < H / BATCH; ++b) {
        const int r0 = (role == 0) ? b * BATCH : H - (b + 1) * BATCH;

        // Issue all 32 loads (8 rows x 4 segments) before consuming -> 1 round trip.
        uint4 v[BATCH][4];
        #pragma unroll
        for (int j = 0; j < BATCH; ++j) {
            const uint4* rp = base + (size_t)(r0 + j) * U4_ROW + t;
            v[j][0] = rp[0];
            v[j][1] = rp[64];
            v[j][2] = rp[128];
            v[j][3] = rp[192];
        }

        #pragma unroll
        for (int j = 0; j < BATCH; ++j) {
            const unsigned any =
                (v[j][0].x | v[j][0].y | v[j][0].z | v[j][0].w) |
                (v[j][1].x | v[j][1].y | v[j][1].z | v[j][1].w) |
                (v[j][2].x | v[j][2].y | v[j][2].z | v[j][2].w) |
                (v[j][3].x | v[j][3].y | v[j][3].z | v[j][3].w);
            if (role == 0) lane_y = min(lane_y, any ? r0 + j : H);
            else           lane_y = max(lane_y, any ? r0 + j : -1);
            c0.x |= v[j][0].x; c0.y |= v[j][0].y; c0.z |= v[j][0].z; c0.w |= v[j][0].w;
            c1.x |= v[j][1].x; c1.y |= v[j][1].y; c1.z |= v[j][1].z; c1.w |= v[j][1].w;
            c2.x |= v[j][2].x; c2.y |= v[j][2].y; c2.z |= v[j][2].z; c2.w |= v[j][2].w;
            c3.x |= v[j][3].x; c3.y |= v[j][3].y; c3.z |= v[j][3].z; c3.w |= v[j][3].w;
        }

        // Break when (y endpoint found) AND (extreme column proven set).
        const bool yf  = (role == 0) ? (lane_y != H) : (lane_y >= 0);
        const bool ext = (role == 0) ? (t == 0  && c0.x != 0)    // col 0
                                     : (t == 63 && c3.w != 0);   // col 1023
        if (__any(yf) && __any(ext)) break;
    }

    // Per-lane extreme column from the accumulated OR (exact under the break
    // rule: early break => candX reduces to 0 / 1023; no break => OR complete).
    int candX;
    const int cbase = 4 * t;
    if (role == 0) {
        int f3 = c3.x ? 768+cbase : c3.y ? 769+cbase : c3.z ? 770+cbase : c3.w ? 771+cbase : W;
        int f2 = c2.x ? 512+cbase : c2.y ? 513+cbase : c2.z ? 514+cbase : c2.w ? 515+cbase : f3;
        int f1 = c1.x ? 256+cbase : c1.y ? 257+cbase : c1.z ? 258+cbase : c1.w ? 259+cbase : f2;
        candX  = c0.x ?     cbase : c0.y ?   1+cbase : c0.z ?   2+cbase : c0.w ?   3+cbase : f1;
    } else {
        int l0 = c0.w ?   3+cbase : c0.z ?   2+cbase : c0.y ?   1+cbase : c0.x ?     cbase : -1;
        int l1 = c1.w ? 259+cbase : c1.z ? 258+cbase : c1.y ? 257+cbase : c1.x ? 256+cbase : l0;
        int l2 = c2.w ? 515+cbase : c2.z ? 514+cbase : c2.y ? 513+cbase : c2.x ? 512+cbase : l1;
        candX  = c3.w ? 771+cbase : c3.z ? 770+cbase : c3.y ? 769+cbase : c3.x ? 768+cbase : l2;
    }

    // 64-lane butterfly reduce (min for top, max for bottom).
    #pragma unroll
    for (int s = 32; s > 0; s >>= 1) {
        const int ox = __shfl_xor(candX, s);
        const int oy = __shfl_xor(lane_y, s);
        if (role == 0) { candX = min(candX, ox); lane_y = min(lane_y, oy); }
        else           { candX = max(candX, ox); lane_y = max(lane_y, oy); }
    }

    if (t == 0) {
        const int o = mask * 4 + (role ? 2 : 0);
        out[o + 0] = (float)candX;   // x1 or x2
        out[o + 1] = (float)lane_y;  // y1 or y2
    }
}

extern "C" void kernel_launch(void* const* d_in, const int* in_sizes, int n_in,
                              void* d_out, int out_size, void* d_ws, size_t ws_size,
                              hipStream_t stream) {
    const uint4* masks = (const uint4*)d_in[0];
    float* out = (float*)d_out;

    dim3 grid(2, N_MASKS);   // (role, mask)
    bbox_ends<<<grid, 64, 0, stream>>>(masks, out);
}